// Round 7
// baseline (562.882 us; speedup 1.0000x reference)
//
#include <hip/hip_runtime.h>
#include <hip/hip_bf16.h>

#define IN_F   2048
#define OUT_F  2048
#define NG     8
#define BATCH  4096
#define KDIM   (IN_F * (NG + 1))   // 18432
#define BK     64
#define NT     (KDIM / BK)         // 288
#define BM     256
#define BN     128
#define ASZ    (BM * BK * 2)       // 32768 B
#define BSZ    (BN * BK * 2)       // 16384 B
#define BUFSZ  (ASZ + BSZ)         // 49152 B

typedef short bf16x8 __attribute__((ext_vector_type(8)));
typedef float f32x4  __attribute__((ext_vector_type(4)));
typedef __attribute__((address_space(3))) unsigned char       lds_u8;
typedef const __attribute__((address_space(1))) unsigned char glb_u8;

__device__ __forceinline__ float sigmoidf_(float v) {
    return 1.0f / (1.0f + __expf(-v));
}

// round-to-nearest-even f32 -> bf16 (as ushort)
__device__ __forceinline__ unsigned short f2bf(float f) {
    unsigned int u = __builtin_bit_cast(unsigned int, f);
    u = (u + 0x7fffu + ((u >> 16) & 1u)) >> 16;
    return (unsigned short)u;
}

// ---------------------------------------------------------------------------
// Kernel 1: activation prep.  A'[b][k] bf16, K-contiguous.
//   k in [0,16384): L1-normalized RBF basis (i*8+g); [16384,18432): x_weighted
// ---------------------------------------------------------------------------
__global__ __launch_bounds__(256) void act_kernel(
    const float* __restrict__ x, const float* __restrict__ fi,
    const float* __restrict__ gr, unsigned short* __restrict__ Abf)
{
    const int base = blockIdx.x * 1024;
    const int tid  = threadIdx.x;
    const int b    = base >> 11;                    // uniform per block
    const float4 g0 = *(const float4*)gr;
    const float4 g1 = *(const float4*)(gr + 4);
    unsigned short* rowp = Abf + (size_t)b * KDIM;

#pragma unroll
    for (int e = 0; e < 4; ++e) {
        const int idx = base + tid + e * 256;
        const int i   = idx & (IN_F - 1);
        const float s  = sigmoidf_(fi[i]);
        const float xw = x[idx] * s;
        // tanh via exp: (e^{2x}-1)/(e^{2x}+1)
        const float ex = __expf(2.0f * xw);
        const float xn = (ex - 1.0f) / (ex + 1.0f);

        float ev[NG];
        float d;
        d = xn - g0.x; ev[0] = __expf(-2.0f * d * d);
        d = xn - g0.y; ev[1] = __expf(-2.0f * d * d);
        d = xn - g0.z; ev[2] = __expf(-2.0f * d * d);
        d = xn - g0.w; ev[3] = __expf(-2.0f * d * d);
        d = xn - g1.x; ev[4] = __expf(-2.0f * d * d);
        d = xn - g1.y; ev[5] = __expf(-2.0f * d * d);
        d = xn - g1.z; ev[6] = __expf(-2.0f * d * d);
        d = xn - g1.w; ev[7] = __expf(-2.0f * d * d);
        float denom = ((ev[0] + ev[1]) + (ev[2] + ev[3])) +
                      ((ev[4] + ev[5]) + (ev[6] + ev[7]));
        const float rinv = 1.0f / fmaxf(denom, 1e-12f);

        union { unsigned short us[8]; int4 v; } pk;
#pragma unroll
        for (int g = 0; g < NG; ++g) pk.us[g] = f2bf(ev[g] * rinv);
        *(int4*)(rowp + i * NG) = pk.v;             // 16B coalesced
        rowp[IN_F * NG + i] = f2bf(xw);             // 2B coalesced
    }
}

// ---------------------------------------------------------------------------
// Kernel 2: weight prep.  W'[o][k] bf16, K-contiguous (B^T layout).
//   k in [0,16384): gate*spline_w; [16384,18432): (1-gate)*base_w
// ---------------------------------------------------------------------------
__global__ __launch_bounds__(256) void wprep_kernel(
    const float* __restrict__ bw, const float* __restrict__ sw,
    const float* __restrict__ ag, unsigned short* __restrict__ Wbf)
{
    const int base = blockIdx.x * 1024;
    const int tid  = threadIdx.x;
    const int o    = base >> 11;                    // uniform per block
    const float gate = sigmoidf_(ag[o]);
    const float og   = 1.0f - gate;
    unsigned short* rowp = Wbf + (size_t)o * KDIM;

#pragma unroll
    for (int e = 0; e < 4; ++e) {
        const int idx = base + tid + e * 256;
        const int i   = idx & (IN_F - 1);
        const float4 s0 = *(const float4*)(sw + (size_t)idx * NG);
        const float4 s1 = *(const float4*)(sw + (size_t)idx * NG + 4);
        union { unsigned short us[8]; int4 v; } pk;
        pk.us[0] = f2bf(gate * s0.x); pk.us[1] = f2bf(gate * s0.y);
        pk.us[2] = f2bf(gate * s0.z); pk.us[3] = f2bf(gate * s0.w);
        pk.us[4] = f2bf(gate * s1.x); pk.us[5] = f2bf(gate * s1.y);
        pk.us[6] = f2bf(gate * s1.z); pk.us[7] = f2bf(gate * s1.w);
        *(int4*)(rowp + i * NG) = pk.v;
        rowp[IN_F * NG + i] = f2bf(og * bw[idx]);
    }
}

// ---------------------------------------------------------------------------
// Kernel 3: bf16 GEMM.  C[4096][2048] = A'[4096][K] * W'[2048][K]^T, K=18432.
// BM=256 BN=128 BK=64, 8 waves = 2M x 2N x 2Ksub; per-wave 128x64 output
// over half-BK (8x4 frags of 16x16x32).  1 phase/K-tile (12 ds_read + 32
// MFMA per wave), 3 LDS buffers (lookahead 2), counted vmcnt(6), T2 XOR
// swizzle both-sides (R2-verified 0-conflict mapping), T5 setprio.
// Epilogue: ks=1 waves dump acc via LDS; ks=0 waves add + store with bias.
// ---------------------------------------------------------------------------
#define MFMA(d, a, b) d = __builtin_amdgcn_mfma_f32_16x16x32_bf16(a, b, d, 0, 0, 0)

#define PHASE_MID()                                            \
    __builtin_amdgcn_sched_barrier(0);                         \
    __builtin_amdgcn_s_barrier();                              \
    asm volatile("s_waitcnt lgkmcnt(0)" ::: "memory");         \
    __builtin_amdgcn_sched_barrier(0);

#define PHASE_END()                                            \
    __builtin_amdgcn_sched_barrier(0);                         \
    __builtin_amdgcn_s_barrier();

#define LDA(m) (*(const bf16x8*)(lds + curBase + oA##m))
#define LDB(n) (*(const bf16x8*)(lds + curBase + oB##n))

// staging: linear LDS dest (lane x 16B), inverse-swizzled global source
#define GLA(j) __builtin_amdgcn_global_load_lds((glb_u8*)(aS##j + ko), \
                   (lds_u8*)(lds + stBase + aO##j), 16, 0, 0)
#define GLB(j) __builtin_amdgcn_global_load_lds((glb_u8*)(bS##j + ko), \
                   (lds_u8*)(lds + stBase + bO##j), 16, 0, 0)

__global__ __launch_bounds__(512, 2) void gemm_kernel(
    const unsigned short* __restrict__ A, const unsigned short* __restrict__ B,
    const float* __restrict__ bb, const float* __restrict__ ag,
    float* __restrict__ C)
{
    __shared__ __align__(16) unsigned char lds[3 * BUFSZ];   // 144 KiB

    const int tid = threadIdx.x;
    const int bid = blockIdx.x;
    // 256 WGs, 8 XCDs -> 32 contiguous tiles per XCD (bijective)
    const int swz = ((bid & 7) << 5) + (bid >> 3);
    const int bm = swz >> 4, bn = swz & 15;

    const int lane = tid & 63, wid = tid >> 6;
    const int ks = wid & 1, wn = (wid >> 1) & 1, wm = wid >> 2;
    const int fr = lane & 15, kg = lane >> 4;
    const int kq = 4 * ks + kg;            // k-chunk index 0..7 within BK

    // ---- staging source pointers (pre-swizzled chunk) + LDS byte offsets
#define MKSA(j)                                                         \
    const int eA##j = tid + (j) * 512;                                  \
    const int rA_##j = eA##j >> 3, cA_##j = (eA##j & 7) ^ (rA_##j & 7); \
    const unsigned short* aS##j = A + (size_t)(bm * BM + rA_##j) * KDIM + cA_##j * 8; \
    const int aO##j = eA##j * 16;
    MKSA(0) MKSA(1) MKSA(2) MKSA(3)
#define MKSB(j)                                                         \
    const int eB##j = tid + (j) * 512;                                  \
    const int rB_##j = eB##j >> 3, cB_##j = (eB##j & 7) ^ (rB_##j & 7); \
    const unsigned short* bS##j = B + (size_t)(bn * BN + rB_##j) * KDIM + cB_##j * 8; \
    const int bO##j = ASZ + eB##j * 16;
    MKSB(0) MKSB(1)

    // ---- ds_read offsets: chunk = kq ^ (row&7)  (R2-verified 0-conflict)
#define MKOA(m)                                                \
    const int rAm##m = wm * 128 + (m) * 16 + fr;               \
    const int oA##m = rAm##m * 128 + ((kq ^ (rAm##m & 7)) << 4);
    MKOA(0) MKOA(1) MKOA(2) MKOA(3) MKOA(4) MKOA(5) MKOA(6) MKOA(7)
#define MKOB(n)                                                \
    const int rBn##n = wn * 64 + (n) * 16 + fr;                \
    const int oB##n = ASZ + rBn##n * 128 + ((kq ^ (rBn##n & 7)) << 4);
    MKOB(0) MKOB(1) MKOB(2) MKOB(3)

    f32x4 acc[8][4] = {};

    // ---- prologue: stage tiles 0 and 1, wait for tile 0
    {
        const int stBase = 0; const long ko = 0;
        GLA(0); GLA(1); GLA(2); GLA(3); GLB(0); GLB(1);
    }
    {
        const int stBase = BUFSZ; const long ko = BK;
        GLA(0); GLA(1); GLA(2); GLA(3); GLB(0); GLB(1);
    }
    asm volatile("s_waitcnt vmcnt(6)" ::: "memory");
    __builtin_amdgcn_sched_barrier(0);
    __builtin_amdgcn_s_barrier();

    int curBase = 0;
    for (int t = 0; t < NT; ++t) {
        const int stBase = (curBase >= BUFSZ) ? (curBase - BUFSZ)
                                              : (curBase + 2 * BUFSZ);
        const bool doSt = (t + 2) < NT;
        const long ko = (long)(t + 2) * BK;

        bf16x8 va0 = LDA(0), va1 = LDA(1), va2 = LDA(2), va3 = LDA(3);
        bf16x8 va4 = LDA(4), va5 = LDA(5), va6 = LDA(6), va7 = LDA(7);
        bf16x8 vb0 = LDB(0), vb1 = LDB(1), vb2 = LDB(2), vb3 = LDB(3);
        if (doSt) { GLA(0); GLA(1); GLA(2); GLA(3); GLB(0); GLB(1); }
        PHASE_MID();
        __builtin_amdgcn_s_setprio(1);
        MFMA(acc[0][0], va0, vb0); MFMA(acc[0][1], va0, vb1);
        MFMA(acc[0][2], va0, vb2); MFMA(acc[0][3], va0, vb3);
        MFMA(acc[1][0], va1, vb0); MFMA(acc[1][1], va1, vb1);
        MFMA(acc[1][2], va1, vb2); MFMA(acc[1][3], va1, vb3);
        MFMA(acc[2][0], va2, vb0); MFMA(acc[2][1], va2, vb1);
        MFMA(acc[2][2], va2, vb2); MFMA(acc[2][3], va2, vb3);
        MFMA(acc[3][0], va3, vb0); MFMA(acc[3][1], va3, vb1);
        MFMA(acc[3][2], va3, vb2); MFMA(acc[3][3], va3, vb3);
        MFMA(acc[4][0], va4, vb0); MFMA(acc[4][1], va4, vb1);
        MFMA(acc[4][2], va4, vb2); MFMA(acc[4][3], va4, vb3);
        MFMA(acc[5][0], va5, vb0); MFMA(acc[5][1], va5, vb1);
        MFMA(acc[5][2], va5, vb2); MFMA(acc[5][3], va5, vb3);
        MFMA(acc[6][0], va6, vb0); MFMA(acc[6][1], va6, vb1);
        MFMA(acc[6][2], va6, vb2); MFMA(acc[6][3], va6, vb3);
        MFMA(acc[7][0], va7, vb0); MFMA(acc[7][1], va7, vb1);
        MFMA(acc[7][2], va7, vb2); MFMA(acc[7][3], va7, vb3);
        __builtin_amdgcn_s_setprio(0);
        if (doSt) { asm volatile("s_waitcnt vmcnt(6)" ::: "memory"); }
        else      { asm volatile("s_waitcnt vmcnt(0)" ::: "memory"); }
        PHASE_END();

        curBase = (curBase == 2 * BUFSZ) ? 0 : (curBase + BUFSZ);
    }

    // ---- cross-wave K-reduction through LDS (staging buffers are dead now;
    //      last PHASE_END barrier guarantees all reads completed)
    const int slot = wm * 2 + wn;          // 0..3, pairs (wm,wn,ks=0/1)
    if (ks == 1) {
#pragma unroll
        for (int m = 0; m < 8; ++m)
#pragma unroll
            for (int n = 0; n < 4; ++n)
                *(f32x4*)(lds + slot * 32768 + (m * 4 + n) * 1024 + lane * 16)
                    = acc[m][n];
    }
    __syncthreads();
    if (ks == 0) {
        const int colb = bn * BN + wn * 64;
        const int rowb = bm * BM + wm * 128;
#pragma unroll
        for (int n = 0; n < 4; ++n) {
            const int col = colb + n * 16 + fr;
            const float gate = sigmoidf_(ag[col]);
            const float bias = (1.0f - gate) * bb[col];
#pragma unroll
            for (int m = 0; m < 8; ++m) {
                const f32x4 part =
                    *(const f32x4*)(lds + slot * 32768 + (m * 4 + n) * 1024 + lane * 16);
                const int r0 = rowb + m * 16 + kg * 4;
#pragma unroll
                for (int j = 0; j < 4; ++j)
                    C[(size_t)(r0 + j) * OUT_F + col] = acc[m][n][j] + part[j] + bias;
            }
        }
    }
}

// ---------------------------------------------------------------------------
extern "C" void kernel_launch(void* const* d_in, const int* in_sizes, int n_in,
                              void* d_out, int out_size, void* d_ws, size_t ws_size,
                              hipStream_t stream)
{
    const float* x  = (const float*)d_in[0];   // [4096,2048]
    const float* bw = (const float*)d_in[1];   // [2048,2048]
    const float* bb = (const float*)d_in[2];   // [2048]
    const float* sw = (const float*)d_in[3];   // [2048,2048,8]
    const float* gr = (const float*)d_in[4];   // [8]
    const float* ag = (const float*)d_in[5];   // [2048]
    const float* fi = (const float*)d_in[6];   // [2048]
    float* out = (float*)d_out;                // [4096,2048] f32

    unsigned short* Abf = (unsigned short*)d_ws;             // [4096][18432] bf16
    unsigned short* Wbf = Abf + (size_t)BATCH * KDIM;        // [2048][18432] bf16

    const size_t need = ((size_t)BATCH + OUT_F) * KDIM * sizeof(unsigned short);
    if (ws_size < need) return;

    act_kernel<<<BATCH * IN_F / 1024, 256, 0, stream>>>(x, fi, gr, Abf);
    wprep_kernel<<<OUT_F * IN_F / 1024, 256, 0, stream>>>(bw, sw, ag, Wbf);
    gemm_kernel<<<(BATCH / BM) * (OUT_F / BN), 512, 0, stream>>>(Abf, Wbf, bb, ag, out);
}

// Round 9
// 533.781 us; speedup vs baseline: 1.0545x; 1.0545x over previous
//
#include <hip/hip_runtime.h>
#include <hip/hip_bf16.h>

#define IN_F   2048
#define OUT_F  2048
#define NG     8
#define BATCH  4096
#define KDIM   (IN_F * (NG + 1))   // 18432
#define BK     64
#define NT     (KDIM / BK)         // 288
#define BM     256
#define BN     128
#define ASZ    (BM * BK * 2)       // 32768 B
#define BSZ    (BN * BK * 2)       // 16384 B
#define BUFSZ  (ASZ + BSZ)         // 49152 B

typedef short bf16x8 __attribute__((ext_vector_type(8)));
typedef float f32x4  __attribute__((ext_vector_type(4)));
typedef __attribute__((address_space(3))) unsigned char       lds_u8;
typedef const __attribute__((address_space(1))) unsigned char glb_u8;

__device__ __forceinline__ float sigmoidf_(float v) {
    return 1.0f / (1.0f + __expf(-v));
}

// round-to-nearest-even f32 -> bf16 (as ushort)
__device__ __forceinline__ unsigned short f2bf(float f) {
    unsigned int u = __builtin_bit_cast(unsigned int, f);
    u = (u + 0x7fffu + ((u >> 16) & 1u)) >> 16;
    return (unsigned short)u;
}

// ---------------------------------------------------------------------------
// Kernel 1: activation prep.  A'[b][k] bf16, K-contiguous.
//   k in [0,16384): L1-normalized RBF basis (i*8+g); [16384,18432): x_weighted
// ---------------------------------------------------------------------------
__global__ __launch_bounds__(256) void act_kernel(
    const float* __restrict__ x, const float* __restrict__ fi,
    const float* __restrict__ gr, unsigned short* __restrict__ Abf)
{
    const int base = blockIdx.x * 1024;
    const int tid  = threadIdx.x;
    const int b    = base >> 11;                    // uniform per block
    const float4 g0 = *(const float4*)gr;
    const float4 g1 = *(const float4*)(gr + 4);
    unsigned short* rowp = Abf + (size_t)b * KDIM;

#pragma unroll
    for (int e = 0; e < 4; ++e) {
        const int idx = base + tid + e * 256;
        const int i   = idx & (IN_F - 1);
        const float s  = sigmoidf_(fi[i]);
        const float xw = x[idx] * s;
        // tanh via exp: (e^{2x}-1)/(e^{2x}+1)
        const float ex = __expf(2.0f * xw);
        const float xn = (ex - 1.0f) / (ex + 1.0f);

        float ev[NG];
        float d;
        d = xn - g0.x; ev[0] = __expf(-2.0f * d * d);
        d = xn - g0.y; ev[1] = __expf(-2.0f * d * d);
        d = xn - g0.z; ev[2] = __expf(-2.0f * d * d);
        d = xn - g0.w; ev[3] = __expf(-2.0f * d * d);
        d = xn - g1.x; ev[4] = __expf(-2.0f * d * d);
        d = xn - g1.y; ev[5] = __expf(-2.0f * d * d);
        d = xn - g1.z; ev[6] = __expf(-2.0f * d * d);
        d = xn - g1.w; ev[7] = __expf(-2.0f * d * d);
        float denom = ((ev[0] + ev[1]) + (ev[2] + ev[3])) +
                      ((ev[4] + ev[5]) + (ev[6] + ev[7]));
        const float rinv = 1.0f / fmaxf(denom, 1e-12f);

        union { unsigned short us[8]; int4 v; } pk;
#pragma unroll
        for (int g = 0; g < NG; ++g) pk.us[g] = f2bf(ev[g] * rinv);
        *(int4*)(rowp + i * NG) = pk.v;             // 16B coalesced
        rowp[IN_F * NG + i] = f2bf(xw);             // 2B coalesced
    }
}

// ---------------------------------------------------------------------------
// Kernel 2: weight prep.  W'[o][k] bf16, K-contiguous (B^T layout).
//   k in [0,16384): gate*spline_w; [16384,18432): (1-gate)*base_w
// ---------------------------------------------------------------------------
__global__ __launch_bounds__(256) void wprep_kernel(
    const float* __restrict__ bw, const float* __restrict__ sw,
    const float* __restrict__ ag, unsigned short* __restrict__ Wbf)
{
    const int base = blockIdx.x * 1024;
    const int tid  = threadIdx.x;
    const int o    = base >> 11;                    // uniform per block
    const float gate = sigmoidf_(ag[o]);
    const float og   = 1.0f - gate;
    unsigned short* rowp = Wbf + (size_t)o * KDIM;

#pragma unroll
    for (int e = 0; e < 4; ++e) {
        const int idx = base + tid + e * 256;
        const int i   = idx & (IN_F - 1);
        const float4 s0 = *(const float4*)(sw + (size_t)idx * NG);
        const float4 s1 = *(const float4*)(sw + (size_t)idx * NG + 4);
        union { unsigned short us[8]; int4 v; } pk;
        pk.us[0] = f2bf(gate * s0.x); pk.us[1] = f2bf(gate * s0.y);
        pk.us[2] = f2bf(gate * s0.z); pk.us[3] = f2bf(gate * s0.w);
        pk.us[4] = f2bf(gate * s1.x); pk.us[5] = f2bf(gate * s1.y);
        pk.us[6] = f2bf(gate * s1.z); pk.us[7] = f2bf(gate * s1.w);
        *(int4*)(rowp + i * NG) = pk.v;
        rowp[IN_F * NG + i] = f2bf(og * bw[idx]);
    }
}

// ---------------------------------------------------------------------------
// Kernel 3: bf16 GEMM.  C[4096][2048] = A'[4096][K] * W'[2048][K]^T, K=18432.
// BM=256 BN=128 BK=64, 8 waves = 2M x 2N x 2Ksub; per-wave 128x64 output.
// SINGLE barrier per K-tile; NO lgkmcnt(0) drain — hipcc emits counted
// lgkmcnt per MFMA cluster, so LDS-read processing of tile t overlaps the
// MFMA pipe (this was the serialization pinning MfmaUtil at ~41%).
// 3 LDS buffers (lookahead 2), counted vmcnt(6), T2 XOR swizzle both-sides
// (R2-verified 0-conflict), T5 setprio.  Split-K epilogue via LDS.
// ---------------------------------------------------------------------------
#define MFMA(d, a, b) d = __builtin_amdgcn_mfma_f32_16x16x32_bf16(a, b, d, 0, 0, 0)

#define LDA(m) (*(const bf16x8*)(lds + curBase + oA##m))
#define LDB(n) (*(const bf16x8*)(lds + curBase + oB##n))

// staging: linear LDS dest (lane x 16B), inverse-swizzled global source
#define GLA(j) __builtin_amdgcn_global_load_lds((glb_u8*)(aS##j + ko), \
                   (lds_u8*)(lds + stBase + aO##j), 16, 0, 0)
#define GLB(j) __builtin_amdgcn_global_load_lds((glb_u8*)(bS##j + ko), \
                   (lds_u8*)(lds + stBase + bO##j), 16, 0, 0)

__global__ __launch_bounds__(512, 2) void gemm_kernel(
    const unsigned short* __restrict__ A, const unsigned short* __restrict__ B,
    const float* __restrict__ bb, const float* __restrict__ ag,
    float* __restrict__ C)
{
    __shared__ __align__(16) unsigned char lds[3 * BUFSZ];   // 144 KiB

    const int tid = threadIdx.x;
    const int bid = blockIdx.x;
    // 256 WGs, 8 XCDs -> 32 contiguous tiles per XCD (bijective)
    const int swz = ((bid & 7) << 5) + (bid >> 3);
    const int bm = swz >> 4, bn = swz & 15;

    const int lane = tid & 63, wid = tid >> 6;
    const int ks = wid & 1, wn = (wid >> 1) & 1, wm = wid >> 2;
    const int fr = lane & 15, kg = lane >> 4;
    const int kq = 4 * ks + kg;            // k-chunk index 0..7 within BK

    // ---- staging source pointers (pre-swizzled chunk) + LDS byte offsets
#define MKSA(j)                                                         \
    const int eA##j = tid + (j) * 512;                                  \
    const int rA_##j = eA##j >> 3, cA_##j = (eA##j & 7) ^ (rA_##j & 7); \
    const unsigned short* aS##j = A + (size_t)(bm * BM + rA_##j) * KDIM + cA_##j * 8; \
    const int aO##j = eA##j * 16;
    MKSA(0) MKSA(1) MKSA(2) MKSA(3)
#define MKSB(j)                                                         \
    const int eB##j = tid + (j) * 512;                                  \
    const int rB_##j = eB##j >> 3, cB_##j = (eB##j & 7) ^ (rB_##j & 7); \
    const unsigned short* bS##j = B + (size_t)(bn * BN + rB_##j) * KDIM + cB_##j * 8; \
    const int bO##j = ASZ + eB##j * 16;
    MKSB(0) MKSB(1)

    // ---- ds_read offsets: chunk = kq ^ (row&7)  (R2-verified 0-conflict)
#define MKOA(m)                                                \
    const int rAm##m = wm * 128 + (m) * 16 + fr;               \
    const int oA##m = rAm##m * 128 + ((kq ^ (rAm##m & 7)) << 4);
    MKOA(0) MKOA(1) MKOA(2) MKOA(3) MKOA(4) MKOA(5) MKOA(6) MKOA(7)
#define MKOB(n)                                                \
    const int rBn##n = wn * 64 + (n) * 16 + fr;                \
    const int oB##n = ASZ + rBn##n * 128 + ((kq ^ (rBn##n & 7)) << 4);
    MKOB(0) MKOB(1) MKOB(2) MKOB(3)

    f32x4 acc[8][4] = {};

    // ---- prologue: stage tiles 0 and 1, wait for tile 0
    {
        const int stBase = 0; const long ko = 0;
        GLA(0); GLA(1); GLA(2); GLA(3); GLB(0); GLB(1);
    }
    {
        const int stBase = BUFSZ; const long ko = BK;
        GLA(0); GLA(1); GLA(2); GLA(3); GLB(0); GLB(1);
    }
    asm volatile("s_waitcnt vmcnt(6)" ::: "memory");
    __builtin_amdgcn_s_barrier();
    __builtin_amdgcn_sched_barrier(0);

    int curBase = 0;
    for (int t = 0; t < NT; ++t) {
        const int stBase = (curBase >= BUFSZ) ? (curBase - BUFSZ)
                                              : (curBase + 2 * BUFSZ);
        const bool doSt = (t + 2) < NT;
        const long ko = (long)(t + 2) * BK;

        // reads issued in consumption order (vb first, then va0..va7);
        // compiler inserts counted lgkmcnt before each dependent cluster,
        // so LDS processing overlaps the MFMA pipe.
        bf16x8 vb0 = LDB(0), vb1 = LDB(1), vb2 = LDB(2), vb3 = LDB(3);
        bf16x8 va0 = LDA(0), va1 = LDA(1), va2 = LDA(2), va3 = LDA(3);
        bf16x8 va4 = LDA(4), va5 = LDA(5), va6 = LDA(6), va7 = LDA(7);
        if (doSt) { GLA(0); GLA(1); GLA(2); GLA(3); GLB(0); GLB(1); }

        __builtin_amdgcn_s_setprio(1);
        MFMA(acc[0][0], va0, vb0); MFMA(acc[0][1], va0, vb1);
        MFMA(acc[0][2], va0, vb2); MFMA(acc[0][3], va0, vb3);
        MFMA(acc[1][0], va1, vb0); MFMA(acc[1][1], va1, vb1);
        MFMA(acc[1][2], va1, vb2); MFMA(acc[1][3], va1, vb3);
        MFMA(acc[2][0], va2, vb0); MFMA(acc[2][1], va2, vb1);
        MFMA(acc[2][2], va2, vb2); MFMA(acc[2][3], va2, vb3);
        MFMA(acc[3][0], va3, vb0); MFMA(acc[3][1], va3, vb1);
        MFMA(acc[3][2], va3, vb2); MFMA(acc[3][3], va3, vb3);
        MFMA(acc[4][0], va4, vb0); MFMA(acc[4][1], va4, vb1);
        MFMA(acc[4][2], va4, vb2); MFMA(acc[4][3], va4, vb3);
        MFMA(acc[5][0], va5, vb0); MFMA(acc[5][1], va5, vb1);
        MFMA(acc[5][2], va5, vb2); MFMA(acc[5][3], va5, vb3);
        MFMA(acc[6][0], va6, vb0); MFMA(acc[6][1], va6, vb1);
        MFMA(acc[6][2], va6, vb2); MFMA(acc[6][3], va6, vb3);
        MFMA(acc[7][0], va7, vb0); MFMA(acc[7][1], va7, vb1);
        MFMA(acc[7][2], va7, vb2); MFMA(acc[7][3], va7, vb3);
        __builtin_amdgcn_s_setprio(0);

        // single barrier per tile: publishes buf[t+1] staged (vmcnt<=6) and
        // separates tile t readers from tile t+2 staging writers.
        __builtin_amdgcn_sched_barrier(0);
        if (doSt) { asm volatile("s_waitcnt vmcnt(6)" ::: "memory"); }
        else      { asm volatile("s_waitcnt vmcnt(0)" ::: "memory"); }
        __builtin_amdgcn_s_barrier();
        __builtin_amdgcn_sched_barrier(0);

        curBase = (curBase == 2 * BUFSZ) ? 0 : (curBase + BUFSZ);
    }

    // ---- cross-wave K-reduction through LDS (staging buffers dead; last
    //      barrier guarantees all reads completed)
    const int slot = wm * 2 + wn;          // 0..3, pairs (wm,wn,ks=0/1)
    if (ks == 1) {
#pragma unroll
        for (int m = 0; m < 8; ++m)
#pragma unroll
            for (int n = 0; n < 4; ++n)
                *(f32x4*)(lds + slot * 32768 + (m * 4 + n) * 1024 + lane * 16)
                    = acc[m][n];
    }
    __syncthreads();
    if (ks == 0) {
        const int colb = bn * BN + wn * 64;
        const int rowb = bm * BM + wm * 128;
#pragma unroll
        for (int n = 0; n < 4; ++n) {
            const int col = colb + n * 16 + fr;
            const float gate = sigmoidf_(ag[col]);
            const float bias = (1.0f - gate) * bb[col];
#pragma unroll
            for (int m = 0; m < 8; ++m) {
                const f32x4 part =
                    *(const f32x4*)(lds + slot * 32768 + (m * 4 + n) * 1024 + lane * 16);
                const int r0 = rowb + m * 16 + kg * 4;
#pragma unroll
                for (int j = 0; j < 4; ++j)
                    C[(size_t)(r0 + j) * OUT_F + col] = acc[m][n][j] + part[j] + bias;
            }
        }
    }
}

// ---------------------------------------------------------------------------
extern "C" void kernel_launch(void* const* d_in, const int* in_sizes, int n_in,
                              void* d_out, int out_size, void* d_ws, size_t ws_size,
                              hipStream_t stream)
{
    const float* x  = (const float*)d_in[0];   // [4096,2048]
    const float* bw = (const float*)d_in[1];   // [2048,2048]
    const float* bb = (const float*)d_in[2];   // [2048]
    const float* sw = (const float*)d_in[3];   // [2048,2048,8]
    const float* gr = (const float*)d_in[4];   // [8]
    const float* ag = (const float*)d_in[5];   // [2048]
    const float* fi = (const float*)d_in[6];   // [2048]
    float* out = (float*)d_out;                // [4096,2048] f32

    unsigned short* Abf = (unsigned short*)d_ws;             // [4096][18432] bf16
    unsigned short* Wbf = Abf + (size_t)BATCH * KDIM;        // [2048][18432] bf16

    const size_t need = ((size_t)BATCH + OUT_F) * KDIM * sizeof(unsigned short);
    if (ws_size < need) return;

    act_kernel<<<BATCH * IN_F / 1024, 256, 0, stream>>>(x, fi, gr, Abf);
    wprep_kernel<<<OUT_F * IN_F / 1024, 256, 0, stream>>>(bw, sw, ag, Wbf);
    gemm_kernel<<<(BATCH / BM) * (OUT_F / BN), 512, 0, stream>>>(Abf, Wbf, bb, ag, out);
}